// Round 1
// baseline (124.582 us; speedup 1.0000x reference)
//
#include <hip/hip_runtime.h>
#include <math.h>

// ---------------------------------------------------------------------------
// Stage 1: xmean[c] = mean over 1024 time samples of channel c  (f64 accum)
// ---------------------------------------------------------------------------
__global__ __launch_bounds__(256) void k_xmean(const float* __restrict__ x,
                                               double* __restrict__ xmean) {
    const int c = blockIdx.x;      // 0..63
    const int t = threadIdx.x;     // 0..255
    const float* row = x + c * 1024;
    double s = 0.0;
#pragma unroll
    for (int u = 0; u < 4; ++u) s += (double)row[t + u * 256];
#pragma unroll
    for (int off = 32; off >= 1; off >>= 1) s += __shfl_down(s, off, 64);
    __shared__ double wsum[4];
    if ((t & 63) == 0) wsum[t >> 6] = s;
    __syncthreads();
    if (t == 0) xmean[c] = (wsum[0] + wsum[1] + wsum[2] + wsum[3]) * (1.0 / 1024.0);
}

// ---------------------------------------------------------------------------
// Stage 2: 64 tiny MLPs.  Block i:
//   att[k]  = xmean[k] * topo[i,k]
//   h[hh]   = relu( sum_k att[k] * W1[i,hh,k] )        (128 outs, 2-way split-K)
//   attn[o] = sigmoid( sum_hh h[hh] * W2[i,o,hh] )     (64 outs, 4-way split-K)
// Weight reads are fully coalesced: a wave covers a contiguous 8KB slab.
// ---------------------------------------------------------------------------
__global__ __launch_bounds__(256) void k_mlp(const float* __restrict__ topo,
                                             const float* __restrict__ W1,
                                             const float* __restrict__ W2,
                                             const double* __restrict__ xmean,
                                             double* __restrict__ attn) {
    const int i = blockIdx.x;      // 0..63
    const int t = threadIdx.x;
    __shared__ double att[64];
    __shared__ double h[128];
    if (t < 64) att[t] = xmean[t] * (double)topo[i * 64 + t];
    __syncthreads();
    {   // h phase: thread -> (hh = t>>1, half = t&1), each sums 32 k's
        const int hh = t >> 1, half = t & 1;
        const float4* wp = (const float4*)(W1 + i * 8192 + hh * 64 + half * 32);
        double acc = 0.0;
#pragma unroll
        for (int q = 0; q < 8; ++q) {
            float4 w = wp[q];
            const int k = half * 32 + q * 4;
            acc += att[k + 0] * (double)w.x + att[k + 1] * (double)w.y +
                   att[k + 2] * (double)w.z + att[k + 3] * (double)w.w;
        }
        acc += __shfl_xor(acc, 1, 64);
        if (half == 0) h[hh] = acc > 0.0 ? acc : 0.0;
    }
    __syncthreads();
    {   // attn phase: thread -> (o = t>>2, part = t&3), each sums 32 hh's
        const int o = t >> 2, part = t & 3;
        const float4* wp = (const float4*)(W2 + i * 8192 + o * 128 + part * 32);
        double acc = 0.0;
#pragma unroll
        for (int q = 0; q < 8; ++q) {
            float4 w = wp[q];
            const int k = part * 32 + q * 4;
            acc += h[k + 0] * (double)w.x + h[k + 1] * (double)w.y +
                   h[k + 2] * (double)w.z + h[k + 3] * (double)w.w;
        }
        acc += __shfl_xor(acc, 1, 64);
        acc += __shfl_xor(acc, 2, 64);
        if (part == 0) attn[i * 64 + o] = 1.0 / (1.0 + exp(-acc));
    }
}

// ---------------------------------------------------------------------------
// Stage 3: fused  y = attn @ x  -> conv1(64->32,K5,p2) -> relu -> pool2
//                               -> conv2(32->16,K5,p2) -> relu -> pool2
// 128 blocks; block b produces conv2-pooled output positions {2b, 2b+1}
// (of 256).  Halo recompute backwards through the chain:
//   conv2-pooled p in [2b,2b+2) -> conv2 pre-pool q in [4b,4b+4)
//   -> conv1-pooled r in [4b-2,4b+6)   (NR=8, zero outside [0,512))
//   -> conv1 pre-pool s in [8b-4,8b+12) (NS=16)
//   -> y columns l in [8b-6,8b+14)      (NL=20, zero outside [0,1024))
// ---------------------------------------------------------------------------
__global__ __launch_bounds__(256) void k_front(const float* __restrict__ x,
                                               const double* __restrict__ attn_g,
                                               const float* __restrict__ c1w,
                                               const float* __restrict__ c1b,
                                               const float* __restrict__ c2w,
                                               const float* __restrict__ c2b,
                                               float* __restrict__ s2out) {
    const int b = blockIdx.x;      // 0..127
    const int t = threadIdx.x;
    const int p0 = b * 2;
    const int lbase = 8 * b - 6;   // y col base (NL=20)
    const int rbase = 4 * b - 2;   // conv1-pooled base (NR=8)

    __shared__ float attn_l[64 * 64];   // 16 KB
    __shared__ float x_l[64 * 20];      // 5 KB
    __shared__ float y_l[64 * 20];      // 5 KB
    __shared__ float w2_l[16 * 32 * 5]; // 10 KB
    __shared__ float b1_l[32];
    __shared__ float b2_l[16];
    __shared__ float c1_l[32 * 8];      // pooled conv1 tile
    __shared__ float c2pre[16 * 4];

    for (int e = t; e < 4096; e += 256) attn_l[e] = (float)attn_g[e];
    for (int e = t; e < 64 * 20; e += 256) {
        const int j = e / 20, li = e % 20, l = lbase + li;
        x_l[e] = (l >= 0 && l < 1024) ? x[j * 1024 + l] : 0.f;
    }
    for (int e = t; e < 2560; e += 256) w2_l[e] = c2w[e];
    if (t < 32) b1_l[t] = c1b[t];
    if (t < 16) b2_l[t] = c2b[t];
    __syncthreads();

    // ---- y = attn @ x  (2 rows x 5 cols register block; 128 active threads)
    if (t < 128) {
        const int ig = t >> 2, lg = t & 3;   // ig 0..31, lg 0..3
        const int i0 = ig * 2, l0 = lg * 5;
        double acc0[5] = {0, 0, 0, 0, 0}, acc1[5] = {0, 0, 0, 0, 0};
        for (int j = 0; j < 64; ++j) {
            const double a0 = (double)attn_l[i0 * 64 + j];
            const double a1 = (double)attn_l[(i0 + 1) * 64 + j];
#pragma unroll
            for (int c = 0; c < 5; ++c) {
                const double xv = (double)x_l[j * 20 + l0 + c];
                acc0[c] += a0 * xv;
                acc1[c] += a1 * xv;
            }
        }
#pragma unroll
        for (int c = 0; c < 5; ++c) {
            y_l[i0 * 20 + l0 + c]       = (float)acc0[c];
            y_l[(i0 + 1) * 20 + l0 + c] = (float)acc1[c];
        }
    }
    __syncthreads();

    // ---- conv1 + relu + pool.  thread -> (oc = t>>3, rg = (t>>2)&1, icq = t&3)
    // rg selects 4 pooled r's (8 pre-pool s's); icq is a 4-way split over ic.
    {
        const int oc = t >> 3, rg = (t >> 2) & 1, icq = t & 3;
        const int sb = 8 * rg;               // local pre-pool s base
        double acc[8] = {0, 0, 0, 0, 0, 0, 0, 0};
        for (int ic = icq * 16; ic < icq * 16 + 16; ++ic) {
            const float* wrow = &c1w[(oc * 64 + ic) * 5];   // global, L1/L2-cached
            const float* yrow = &y_l[ic * 20 + sb];
            float yv[12];
#pragma unroll
            for (int c = 0; c < 12; ++c) yv[c] = yrow[c];
            float wv[5];
#pragma unroll
            for (int k = 0; k < 5; ++k) wv[k] = wrow[k];
#pragma unroll
            for (int k = 0; k < 5; ++k) {
                const double w = (double)wv[k];
#pragma unroll
                for (int u = 0; u < 8; ++u) acc[u] += w * (double)yv[u + k];
            }
        }
#pragma unroll
        for (int u = 0; u < 8; ++u) {
            acc[u] += __shfl_xor(acc[u], 1, 64);
            acc[u] += __shfl_xor(acc[u], 2, 64);
        }
        if (icq == 0) {
            const double bias = (double)b1_l[oc];
#pragma unroll
            for (int v = 0; v < 4; ++v) {
                const double v0 = acc[2 * v] + bias, v1 = acc[2 * v + 1] + bias;
                const double m = fmax(fmax(v0, v1), 0.0);
                const int r_idx = rg * 4 + v;
                const int r = rbase + r_idx;
                c1_l[oc * 8 + r_idx] = (r >= 0 && r < 512) ? (float)m : 0.f;
            }
        }
    }
    __syncthreads();

    // ---- conv2 + relu (pre-pool): 16 oc x 4 q = 64 outputs
    if (t < 64) {
        const int oc = t >> 2, q_idx = t & 3;
        double acc = (double)b2_l[oc];
        for (int ic = 0; ic < 32; ++ic) {
            const float* wrow = &w2_l[(oc * 32 + ic) * 5];
            const float* crow = &c1_l[ic * 8 + q_idx];   // local r_idx = q_idx + k
#pragma unroll
            for (int k = 0; k < 5; ++k) acc += (double)wrow[k] * (double)crow[k];
        }
        c2pre[t] = (float)fmax(acc, 0.0);
    }
    __syncthreads();
    // ---- pool -> (16, 256) global
    if (t < 32) {
        const int oc = t >> 1, p_idx = t & 1;
        const float m = fmaxf(c2pre[oc * 4 + 2 * p_idx], c2pre[oc * 4 + 2 * p_idx + 1]);
        s2out[oc * 256 + p0 + p_idx] = m;
    }
}

// ---------------------------------------------------------------------------
// Stage 4 (single block): conv3..conv6 (+relu+pool each) + final dot.
// ---------------------------------------------------------------------------
__global__ __launch_bounds__(256) void k_tail(const float* __restrict__ s2,
                                              const float* __restrict__ c3w, const float* __restrict__ c3b,
                                              const float* __restrict__ c4w, const float* __restrict__ c4b,
                                              const float* __restrict__ c5w, const float* __restrict__ c5b,
                                              const float* __restrict__ c6w, const float* __restrict__ c6b,
                                              const float* __restrict__ ow,  const float* __restrict__ ob,
                                              float* __restrict__ out) {
    const int t = threadIdx.x;
    __shared__ __align__(16) float s2p[16 * 264];  // col idx +4 left pad, +4 right pad, zeroed
    __shared__ float w3_l[640], b3_l[8];
    __shared__ float s3_l[8 * 128];
    __shared__ float w4_l[160], b4_l[4];
    __shared__ float s4_l[4 * 64];
    __shared__ float w5_l[40],  b5_l[2];
    __shared__ float s5_l[2 * 32];
    __shared__ float w6_l[10],  b6_l[1];
    __shared__ float s6_l[16];
    __shared__ float ow_l[16],  ob_l[1];

    for (int e = t; e < 16 * 264; e += 256) s2p[e] = 0.f;
    for (int e = t; e < 640; e += 256) w3_l[e] = c3w[e];
    if (t < 8)   b3_l[t] = c3b[t];
    if (t < 160) w4_l[t] = c4w[t];
    if (t < 4)   b4_l[t] = c4b[t];
    if (t < 40)  w5_l[t] = c5w[t];
    if (t < 2)   b5_l[t] = c5b[t];
    if (t < 10)  w6_l[t] = c6w[t];
    if (t == 0)  b6_l[0] = c6b[0];
    if (t < 16)  ow_l[t] = ow[t];
    if (t == 0)  ob_l[0] = ob[0];
    __syncthreads();
    for (int e = t; e < 4096; e += 256) {
        const int ic = e >> 8, col = e & 255;
        s2p[ic * 264 + 4 + col] = s2[e];
    }
    __syncthreads();

    // ---- conv3 (16->8, L 256 -> pooled 128): thread -> (oc = t>>5, pg = t&31)
    // pg covers 4 pooled p's = 8 pre-pool s's; window of 16 cols (float4 x4).
    {
        const int oc = t >> 5, pg = t & 31;
        double acc[8] = {0, 0, 0, 0, 0, 0, 0, 0};
        for (int ic = 0; ic < 16; ++ic) {
            const float4* win4 = (const float4*)&s2p[ic * 264 + 8 * pg];  // cols 8pg-4 .. 8pg+11
            float win[16];
#pragma unroll
            for (int q = 0; q < 4; ++q) {
                const float4 v = win4[q];
                win[4 * q] = v.x; win[4 * q + 1] = v.y; win[4 * q + 2] = v.z; win[4 * q + 3] = v.w;
            }
            const float* wrow = &w3_l[(oc * 16 + ic) * 5];
#pragma unroll
            for (int k = 0; k < 5; ++k) {
                const double w = (double)wrow[k];
#pragma unroll
                for (int u = 0; u < 8; ++u) acc[u] += w * (double)win[u + k + 2];
            }
        }
        const double bias = (double)b3_l[oc];
#pragma unroll
        for (int v = 0; v < 4; ++v) {
            const double v0 = acc[2 * v] + bias, v1 = acc[2 * v + 1] + bias;
            s3_l[oc * 128 + pg * 4 + v] = (float)fmax(fmax(v0, v1), 0.0);
        }
    }
    __syncthreads();

    // ---- conv4 (8->4, L 128 -> pooled 64): thread -> (oc = t>>6, p = t&63)
    {
        const int oc = t >> 6, p = t & 63;
        double a0 = (double)b4_l[oc], a1 = a0;
        for (int ic = 0; ic < 8; ++ic) {
            const float* wrow = &w4_l[(oc * 8 + ic) * 5];
            const float* srow = &s3_l[ic * 128];
            float c[6];
#pragma unroll
            for (int u = 0; u < 6; ++u) {
                const int col = 2 * p - 2 + u;
                c[u] = (col >= 0 && col < 128) ? srow[col] : 0.f;
            }
#pragma unroll
            for (int k = 0; k < 5; ++k) {
                const double w = (double)wrow[k];
                a0 += w * (double)c[k];
                a1 += w * (double)c[k + 1];
            }
        }
        s4_l[oc * 64 + p] = (float)fmax(fmax(a0, a1), 0.0);
    }
    __syncthreads();

    // ---- conv5 (4->2, L 64 -> pooled 32)
    if (t < 64) {
        const int oc = t >> 5, p = t & 31;
        double a0 = (double)b5_l[oc], a1 = a0;
        for (int ic = 0; ic < 4; ++ic) {
            const float* wrow = &w5_l[(oc * 4 + ic) * 5];
            const float* srow = &s4_l[ic * 64];
            float c[6];
#pragma unroll
            for (int u = 0; u < 6; ++u) {
                const int col = 2 * p - 2 + u;
                c[u] = (col >= 0 && col < 64) ? srow[col] : 0.f;
            }
#pragma unroll
            for (int k = 0; k < 5; ++k) {
                const double w = (double)wrow[k];
                a0 += w * (double)c[k];
                a1 += w * (double)c[k + 1];
            }
        }
        s5_l[oc * 32 + p] = (float)fmax(fmax(a0, a1), 0.0);
    }
    __syncthreads();

    // ---- conv6 (2->1, L 32 -> pooled 16)
    if (t < 16) {
        const int p = t;
        double a0 = (double)b6_l[0], a1 = a0;
        for (int ic = 0; ic < 2; ++ic) {
            const float* wrow = &w6_l[ic * 5];
            const float* srow = &s5_l[ic * 32];
            float c[6];
#pragma unroll
            for (int u = 0; u < 6; ++u) {
                const int col = 2 * p - 2 + u;
                c[u] = (col >= 0 && col < 32) ? srow[col] : 0.f;
            }
#pragma unroll
            for (int k = 0; k < 5; ++k) {
                const double w = (double)wrow[k];
                a0 += w * (double)c[k];
                a1 += w * (double)c[k + 1];
            }
        }
        s6_l[p] = (float)fmax(fmax(a0, a1), 0.0);
    }
    __syncthreads();

    // ---- final dot (16) + bias
    if (t == 0) {
        double acc = (double)ob_l[0];
#pragma unroll
        for (int l = 0; l < 16; ++l) acc += (double)ow_l[l] * (double)s6_l[l];
        out[0] = (float)acc;
    }
}

// ---------------------------------------------------------------------------
extern "C" void kernel_launch(void* const* d_in, const int* in_sizes, int n_in,
                              void* d_out, int out_size, void* d_ws, size_t ws_size,
                              hipStream_t stream) {
    (void)in_sizes; (void)n_in; (void)out_size; (void)ws_size;
    const float* x    = (const float*)d_in[0];
    const float* topo = (const float*)d_in[1];
    const float* W1   = (const float*)d_in[2];
    const float* W2   = (const float*)d_in[3];
    const float* c1w  = (const float*)d_in[4];
    const float* c1b  = (const float*)d_in[5];
    const float* c2w  = (const float*)d_in[6];
    const float* c2b  = (const float*)d_in[7];
    const float* c3w  = (const float*)d_in[8];
    const float* c3b  = (const float*)d_in[9];
    const float* c4w  = (const float*)d_in[10];
    const float* c4b  = (const float*)d_in[11];
    const float* c5w  = (const float*)d_in[12];
    const float* c5b  = (const float*)d_in[13];
    const float* c6w  = (const float*)d_in[14];
    const float* c6b  = (const float*)d_in[15];
    const float* ow   = (const float*)d_in[16];
    const float* ob   = (const float*)d_in[17];

    double* ws_xmean = (double*)d_ws;          // 64 doubles
    double* ws_attn  = ws_xmean + 64;          // 4096 doubles
    float*  ws_s2    = (float*)(ws_attn + 4096); // 4096 floats (16 x 256)

    k_xmean<<<64, 256, 0, stream>>>(x, ws_xmean);
    k_mlp<<<64, 256, 0, stream>>>(topo, W1, W2, ws_xmean, ws_attn);
    k_front<<<128, 256, 0, stream>>>(x, ws_attn, c1w, c1b, c2w, c2b, ws_s2);
    k_tail<<<1, 256, 0, stream>>>(ws_s2, c3w, c3b, c4w, c4b, c5w, c5b,
                                  c6w, c6b, ow, ob, (float*)d_out);
}